// Round 5
// baseline (673.760 us; speedup 1.0000x reference)
//
#include <hip/hip_runtime.h>
#include <hip/hip_bf16.h>

#define NN 50000
#define NE 1600000
#define FIN 128
#define FOUT 64
#define ALPHA 0.2f

// ---------- int width sniffer: int32 (0) vs int64 (1) ----------
__global__ void k_sniff(const int* __restrict__ edge32, int* __restrict__ iflag) {
    __shared__ int zodd;
    if (threadIdx.x == 0) zodd = 0;
    __syncthreads();
    int z = 0;
    for (int i = threadIdx.x; i < 2048; i += 256)
        if (edge32[2 * i + 1] == 0) z++;        // int64 high words are always 0
    atomicAdd(&zodd, z);
    __syncthreads();
    if (threadIdx.x == 0) *iflag = (zodd > 2000) ? 1 : 0;
}

__device__ inline int ldi(const void* p, size_t i, int isi64) {
    int v = isi64 ? (int)((const long long*)p)[i] : ((const int*)p)[i];
    return v < 0 ? 0 : (v >= NN ? NN - 1 : v);  // clamp: no data-dependent OOB
}

// ---------- K0: u = W @ {a1l,a1r,a2l,a2r}  (4 x 128 f32) ----------
__global__ void k_u(const float* __restrict__ W, const float* __restrict__ a1,
                    const float* __restrict__ a2, float* __restrict__ u) {
    int k = threadIdx.x;  // 0..127
    float u1 = 0.f, u2 = 0.f, u3 = 0.f, u4 = 0.f;
    for (int j = 0; j < FOUT; j++) {
        float w = W[k * FOUT + j];
        u1 += w * a1[j];
        u2 += w * a1[FOUT + j];
        u3 += w * a2[j];
        u4 += w * a2[FOUT + j];
    }
    u[k] = u1; u[128 + k] = u2; u[256 + k] = u3; u[384 + k] = u4;
}

// ---------- K1: h = input @ W  (N x 64 f32, staged in out0 region) ----------
__global__ __launch_bounds__(256) void k_gemm(const float* __restrict__ X,
                                              const float* __restrict__ W,
                                              float* __restrict__ h) {
    __shared__ float wlds[FIN * FOUT];      // 32 KB
    __shared__ float xlds[4][4][FIN];       // 8 KB
    int tid = threadIdx.x;
    for (int i = tid; i < FIN * FOUT; i += 256) wlds[i] = W[i];
    int wave = tid >> 6, lane = tid & 63;
    int base = blockIdx.x * 16 + wave * 4;  // 3125*16 = 50000 exact
    for (int n0 = 0; n0 < 4; n0++) {
        float2 b = ((const float2*)(X + (size_t)(base + n0) * FIN))[lane];
        xlds[wave][n0][2 * lane] = b.x;
        xlds[wave][n0][2 * lane + 1] = b.y;
    }
    __syncthreads();
    float a0 = 0.f, a1v = 0.f, a2v = 0.f, a3 = 0.f;
    for (int k = 0; k < FIN; k++) {
        float w = wlds[k * FOUT + lane];
        a0  += xlds[wave][0][k] * w;
        a1v += xlds[wave][1][k] * w;
        a2v += xlds[wave][2][k] * w;
        a3  += xlds[wave][3][k] * w;
    }
    h[(size_t)(base + 0) * FOUT + lane] = a0;
    h[(size_t)(base + 1) * FOUT + lane] = a1v;
    h[(size_t)(base + 2) * FOUT + lane] = a2v;
    h[(size_t)(base + 3) * FOUT + lane] = a3;
}

// ---------- K1b: per-node score scalars (one wave per node) ----------
__global__ __launch_bounds__(256) void k_svec(const float* __restrict__ input,
                                              const float* __restrict__ p_h,
                                              const float* __restrict__ new_h,
                                              const float* __restrict__ u,
                                              float* __restrict__ s1, float* __restrict__ s2,
                                              float* __restrict__ s3, float* __restrict__ s4) {
    int lane = threadIdx.x & 63;
    int v = blockIdx.x * 4 + (threadIdx.x >> 6);  // 12500*4 = 50000 exact
    size_t row = (size_t)v * FIN;
    float2 bi = ((const float2*)(input + row))[lane];
    float2 bp = ((const float2*)(p_h   + row))[lane];
    float2 bn = ((const float2*)(new_h + row))[lane];
    float p1 = bi.x * u[2 * lane]       + bi.y * u[2 * lane + 1];
    float p2 = bp.x * u[128 + 2 * lane] + bp.y * u[128 + 2 * lane + 1];
    float p3 = bn.x * u[256 + 2 * lane] + bn.y * u[256 + 2 * lane + 1];
    float p4 = bi.x * u[384 + 2 * lane] + bi.y * u[384 + 2 * lane + 1];
#pragma unroll
    for (int off = 32; off > 0; off >>= 1) {
        p1 += __shfl_down(p1, off, 64);
        p2 += __shfl_down(p2, off, 64);
        p3 += __shfl_down(p3, off, 64);
        p4 += __shfl_down(p4, off, 64);
    }
    if (lane == 0) { s1[v] = p1; s2[v] = p2; s3[v] = p3; s4[v] = p4; }
}

// ---------- K2: col score + exp + segment max ----------
__global__ void k_colscore(const float* __restrict__ s1, const float* __restrict__ s2,
                           const void* __restrict__ edge_col, const void* __restrict__ row_i,
                           const int* __restrict__ iflag,
                           float* __restrict__ ec, unsigned int* __restrict__ m) {
    int i = blockIdx.x * 256 + threadIdx.x;
    if (i >= NN) return;
    int i64 = *iflag;
    float cs = s1[ldi(edge_col, i, i64)] + s2[i];
    float l = cs > 0.f ? cs : ALPHA * cs;
    float e = expf(-l);                // > 0 always
    ec[i] = e;
    atomicMax(&m[ldi(row_i, i, i64)], __float_as_uint(e));  // init 0, e>0 -> valid
}

// ---------- K3: ex = exp(ec - m) in place; segment sum ----------
__global__ void k_expsum(float* __restrict__ ec, const unsigned int* __restrict__ m,
                         const void* __restrict__ row_i, const int* __restrict__ iflag,
                         float* __restrict__ ssum) {
    int i = blockIdx.x * 256 + threadIdx.x;
    if (i >= NN) return;
    int r = ldi(row_i, i, *iflag);
    float e = expf(ec[i] - __uint_as_float(m[r]));
    ec[i] = e;
    atomicAdd(&ssum[r], e);
}

// ---------- K4: normalize ----------
__global__ void k_norm(const float* __restrict__ ex, const float* __restrict__ ssum,
                       const void* __restrict__ row_i, const int* __restrict__ iflag,
                       float* __restrict__ ecs) {
    int i = blockIdx.x * 256 + threadIdx.x;
    if (i >= NN) return;
    ecs[i] = ex[i] / (ssum[ldi(row_i, i, *iflag)] + 1e-16f);
}

// ---------- K5: per-edge attention + scatter; numerator -> out2 (f32, in place later) ----
__global__ __launch_bounds__(256) void k_edge(const float* __restrict__ s3, const float* __restrict__ s4,
                                              const float* __restrict__ ecs,
                                              const void* __restrict__ edge, const void* __restrict__ row_resort,
                                              const int* __restrict__ iflag,
                                              const float* __restrict__ h,
                                              float* __restrict__ edge_e, float* __restrict__ e_rowsum,
                                              float* __restrict__ h_acc) {
    int lane = threadIdx.x & 63;
    int e = blockIdx.x * 4 + (threadIdx.x >> 6);   // 400000*4 = E exact
    int i64 = *iflag;
    int e0 = ldi(edge, e, i64);
    int e1 = ldi(edge, (size_t)NE + e, i64);
    int rr = ldi(row_resort, e, i64);
    float rs = s3[rr] + s4[e1];
    float l = rs > 0.f ? rs : ALPHA * rs;
    float ee = expf(-l) * ecs[rr];
    float hv = h[(size_t)e1 * FOUT + lane];
    atomicAdd(&h_acc[(size_t)e0 * FOUT + lane], ee * hv);
    if (lane == 0) {
        edge_e[e] = ee;                 // numerator into out2 region
        atomicAdd(&e_rowsum[e0], ee);
    }
}

// ---------- K6: out0 = elu(h_acc / rowsum)  (f32) ----------
__global__ __launch_bounds__(256) void k_nodeout(const float* __restrict__ h_acc,
                                                 const float* __restrict__ e_rowsum,
                                                 float* __restrict__ out0) {
    int lane = threadIdx.x & 63;
    int v = blockIdx.x * 4 + (threadIdx.x >> 6);
    float rs = e_rowsum[v];
    rs += (rs == 0.f) ? 1.f : 0.f;
    float hp = h_acc[(size_t)v * FOUT + lane] / rs;
    float o = hp > 0.f ? hp : expm1f(hp);
    out0[(size_t)v * FOUT + lane] = o;
}

// ---------- K7: out2 = numerator / rowsum, in place (f32) ----------
__global__ void k_att(const void* __restrict__ edge, const int* __restrict__ iflag,
                      const float* __restrict__ e_rowsum, float* __restrict__ out2) {
    int e = blockIdx.x * 256 + threadIdx.x;  // 6250*256 = E exact
    float rs = e_rowsum[ldi(edge, e, *iflag)];
    rs += (rs == 0.f) ? 1.f : 0.f;
    out2[e] = out2[e] / rs;
}

// ---------- K8: out1 = float(edge), runs LAST (overwrites h_acc scratch) ----------
__global__ void k_edgecopy(const void* __restrict__ edge, const int* __restrict__ iflag,
                           float* __restrict__ out1) {
    int i = blockIdx.x * 256 + threadIdx.x;  // 12500*256 = 2E exact
    int i64 = *iflag;
    int v = i64 ? (int)((const long long*)edge)[i] : ((const int*)edge)[i];
    out1[i] = (float)v;
}

extern "C" void kernel_launch(void* const* d_in, const int* in_sizes, int n_in,
                              void* d_out, int out_size, void* d_ws, size_t ws_size,
                              hipStream_t stream) {
    // Resolve inputs by element count (all distinct): 6.4M x3 in order, 3.2M,
    // 100k, 50k, 1.6M, 8192, 128 x2 in order.
    int ix[3] = {0, 1, 2}; int nx = 0;
    int iE = 3, iCol = 4, iRowI = 5, iRes = 6, iW = 8, iA1 = 9, iA2 = 10;
    bool a1seen = false;
    for (int i = 0; i < n_in; i++) {
        int s = in_sizes[i];
        if (s == NN * FIN) { if (nx < 3) ix[nx++] = i; }
        else if (s == 2 * NE) iE = i;
        else if (s == 2 * NN) iCol = i;
        else if (s == NN) iRowI = i;
        else if (s == NE) iRes = i;
        else if (s == FIN * FOUT) iW = i;
        else if (s == 2 * FOUT) { if (!a1seen) { iA1 = i; a1seen = true; } else iA2 = i; }
    }
    const float* input = (const float*)d_in[ix[0]];
    const float* p_h   = (const float*)d_in[ix[1]];
    const float* new_h = (const float*)d_in[ix[2]];
    const void* edge       = d_in[iE];
    const void* edge_col   = d_in[iCol];
    const void* row_i      = d_in[iRowI];
    const void* row_resort = d_in[iRes];
    const float* W  = (const float*)d_in[iW];
    const float* a1 = (const float*)d_in[iA1];
    const float* a2 = (const float*)d_in[iA2];

    // Outputs are FLOAT32, concatenated: out0 (N*64), out1 (2E), out2 (E).
    float* out0 = (float*)d_out;                      // f32 [0, 3.2M)
    float* out1 = out0 + (size_t)NN * FOUT;           // f32 [3.2M, 6.4M)
    float* out2 = out1 + (size_t)2 * NE;              // f32 [6.4M, 8M)

    // Big scratch lives inside d_out (stream-ordered reuse):
    //   h      -> out0 region (consumed by k_edge, then overwritten by k_nodeout)
    //   h_acc  -> out1 region (zeroed; k_edge atomics; k_nodeout reads; k_edgecopy overwrites LAST)
    //   edge_e -> out2 region (k_edge writes numerator; k_att divides in place)
    float* h      = out0;
    float* h_acc  = out1;
    float* edge_e = out2;

    // ws: 9*N + 512 + 1 floats ~= 1.8 MB
    float* s1  = (float*)d_ws;
    float* s2  = s1 + NN;
    float* s3  = s2 + NN;
    float* s4  = s3 + NN;
    float* ec  = s4 + NN;                  // reused in place as ex
    float* ecs = ec + NN;
    float* mseg  = ecs + NN;               // zero (atomicMax uint bits)
    float* ssum  = mseg + NN;              // zero
    float* ersum = ssum + NN;              // zero
    float* u     = ersum + NN;             // 512
    int*   iflag = (int*)(u + 512);

    hipMemsetAsync(h_acc, 0, (size_t)NN * FOUT * sizeof(float), stream);
    hipMemsetAsync(mseg, 0, (size_t)3 * NN * sizeof(float), stream);

    k_sniff<<<1, 256, 0, stream>>>((const int*)edge, iflag);
    k_u<<<1, 128, 0, stream>>>(W, a1, a2, u);
    k_gemm<<<NN / 16, 256, 0, stream>>>(input, W, h);
    k_svec<<<NN / 4, 256, 0, stream>>>(input, p_h, new_h, u, s1, s2, s3, s4);
    k_colscore<<<(NN + 255) / 256, 256, 0, stream>>>(s1, s2, edge_col, row_i, iflag, ec, (unsigned int*)mseg);
    k_expsum<<<(NN + 255) / 256, 256, 0, stream>>>(ec, (const unsigned int*)mseg, row_i, iflag, ssum);
    k_norm<<<(NN + 255) / 256, 256, 0, stream>>>(ec, ssum, row_i, iflag, ecs);
    k_edge<<<NE / 4, 256, 0, stream>>>(s3, s4, ecs, edge, row_resort, iflag, h, edge_e, ersum, h_acc);
    k_nodeout<<<NN / 4, 256, 0, stream>>>(h_acc, ersum, out0);
    k_att<<<NE / 256, 256, 0, stream>>>(edge, iflag, ersum, out2);
    k_edgecopy<<<2 * NE / 256, 256, 0, stream>>>(edge, iflag, out1);
}

// Round 6
// 423.306 us; speedup vs baseline: 1.5917x; 1.5917x over previous
//
#include <hip/hip_runtime.h>

#define NN 50000
#define NE 1600000
#define FIN 128
#define FOUT 64
#define ALPHA 0.2f

// ---------- int width sniffer: int32 (0) vs int64 (1) ----------
__global__ void k_sniff(const int* __restrict__ edge32, int* __restrict__ iflag) {
    __shared__ int zodd;
    if (threadIdx.x == 0) zodd = 0;
    __syncthreads();
    int z = 0;
    for (int i = threadIdx.x; i < 2048; i += 256)
        if (edge32[2 * i + 1] == 0) z++;        // int64 high words are always 0
    atomicAdd(&zodd, z);
    __syncthreads();
    if (threadIdx.x == 0) *iflag = (zodd > 2000) ? 1 : 0;
}

__device__ inline int ldi(const void* p, size_t i, int isi64) {
    int v = isi64 ? (int)((const long long*)p)[i] : ((const int*)p)[i];
    return v < 0 ? 0 : (v >= NN ? NN - 1 : v);  // clamp: no data-dependent OOB
}

// ---------- K0: u = W @ {a1l,a1r,a2l,a2r} ----------
__global__ void k_u(const float* __restrict__ W, const float* __restrict__ a1,
                    const float* __restrict__ a2, float* __restrict__ u) {
    int k = threadIdx.x;  // 0..127
    float u1 = 0.f, u2 = 0.f, u3 = 0.f, u4 = 0.f;
    for (int j = 0; j < FOUT; j++) {
        float w = W[k * FOUT + j];
        u1 += w * a1[j];
        u2 += w * a1[FOUT + j];
        u3 += w * a2[j];
        u4 += w * a2[FOUT + j];
    }
    u[k] = u1; u[128 + k] = u2; u[256 + k] = u3; u[384 + k] = u4;
}

// ---------- K1: h = input @ W  (N x 64 f32, in ws) ----------
__global__ __launch_bounds__(256) void k_gemm(const float* __restrict__ X,
                                              const float* __restrict__ W,
                                              float* __restrict__ h) {
    __shared__ float wlds[FIN * FOUT];      // 32 KB
    __shared__ float xlds[4][4][FIN];       // 8 KB
    int tid = threadIdx.x;
    for (int i = tid; i < FIN * FOUT; i += 256) wlds[i] = W[i];
    int wave = tid >> 6, lane = tid & 63;
    int base = blockIdx.x * 16 + wave * 4;  // 3125*16 = 50000 exact
    for (int n0 = 0; n0 < 4; n0++) {
        float2 b = ((const float2*)(X + (size_t)(base + n0) * FIN))[lane];
        xlds[wave][n0][2 * lane] = b.x;
        xlds[wave][n0][2 * lane + 1] = b.y;
    }
    __syncthreads();
    float a0 = 0.f, a1v = 0.f, a2v = 0.f, a3 = 0.f;
    for (int k = 0; k < FIN; k++) {
        float w = wlds[k * FOUT + lane];
        a0  += xlds[wave][0][k] * w;
        a1v += xlds[wave][1][k] * w;
        a2v += xlds[wave][2][k] * w;
        a3  += xlds[wave][3][k] * w;
    }
    h[(size_t)(base + 0) * FOUT + lane] = a0;
    h[(size_t)(base + 1) * FOUT + lane] = a1v;
    h[(size_t)(base + 2) * FOUT + lane] = a2v;
    h[(size_t)(base + 3) * FOUT + lane] = a3;
}

// ---------- K1b: per-node score scalars (one wave per node) ----------
__global__ __launch_bounds__(256) void k_svec(const float* __restrict__ input,
                                              const float* __restrict__ p_h,
                                              const float* __restrict__ new_h,
                                              const float* __restrict__ u,
                                              float* __restrict__ s1, float* __restrict__ s2,
                                              float* __restrict__ s3, float* __restrict__ s4) {
    int lane = threadIdx.x & 63;
    int v = blockIdx.x * 4 + (threadIdx.x >> 6);
    size_t row = (size_t)v * FIN;
    float2 bi = ((const float2*)(input + row))[lane];
    float2 bp = ((const float2*)(p_h   + row))[lane];
    float2 bn = ((const float2*)(new_h + row))[lane];
    float p1 = bi.x * u[2 * lane]       + bi.y * u[2 * lane + 1];
    float p2 = bp.x * u[128 + 2 * lane] + bp.y * u[128 + 2 * lane + 1];
    float p3 = bn.x * u[256 + 2 * lane] + bn.y * u[256 + 2 * lane + 1];
    float p4 = bi.x * u[384 + 2 * lane] + bi.y * u[384 + 2 * lane + 1];
#pragma unroll
    for (int off = 32; off > 0; off >>= 1) {
        p1 += __shfl_down(p1, off, 64);
        p2 += __shfl_down(p2, off, 64);
        p3 += __shfl_down(p3, off, 64);
        p4 += __shfl_down(p4, off, 64);
    }
    if (lane == 0) { s1[v] = p1; s2[v] = p2; s3[v] = p3; s4[v] = p4; }
}

// ---------- K2: col score + exp + segment max ----------
__global__ void k_colscore(const float* __restrict__ s1, const float* __restrict__ s2,
                           const void* __restrict__ edge_col, const void* __restrict__ row_i,
                           const int* __restrict__ iflag,
                           float* __restrict__ ec, unsigned int* __restrict__ m) {
    int i = blockIdx.x * 256 + threadIdx.x;
    if (i >= NN) return;
    int i64 = *iflag;
    float cs = s1[ldi(edge_col, i, i64)] + s2[i];
    float l = cs > 0.f ? cs : ALPHA * cs;
    float e = expf(-l);                // > 0 always
    ec[i] = e;
    atomicMax(&m[ldi(row_i, i, i64)], __float_as_uint(e));  // init 0, e>0 -> valid
}

// ---------- K3: ex = exp(ec - m) in place; segment sum ----------
__global__ void k_expsum(float* __restrict__ ec, const unsigned int* __restrict__ m,
                         const void* __restrict__ row_i, const int* __restrict__ iflag,
                         float* __restrict__ ssum) {
    int i = blockIdx.x * 256 + threadIdx.x;
    if (i >= NN) return;
    int r = ldi(row_i, i, *iflag);
    float e = expf(ec[i] - __uint_as_float(m[r]));
    ec[i] = e;
    atomicAdd(&ssum[r], e);
}

// ---------- K4: normalize ----------
__global__ void k_norm(const float* __restrict__ ex, const float* __restrict__ ssum,
                       const void* __restrict__ row_i, const int* __restrict__ iflag,
                       float* __restrict__ ecs) {
    int i = blockIdx.x * 256 + threadIdx.x;
    if (i >= NN) return;
    ecs[i] = ex[i] / (ssum[ldi(row_i, i, *iflag)] + 1e-16f);
}

// ---------- K5a: histogram of destinations ----------
__global__ void k_hist(const void* __restrict__ edge, const int* __restrict__ iflag,
                       int* __restrict__ cnt) {
    int e = blockIdx.x * 256 + threadIdx.x;   // 6250*256 = NE exact
    atomicAdd(&cnt[ldi(edge, e, *iflag)], 1);
}

// ---------- K5b: exclusive scan, 3 phases (98 blocks x 512 covers 50176) ----------
__global__ __launch_bounds__(512) void k_scan1(const int* __restrict__ cnt,
                                               int* __restrict__ start, int* __restrict__ bsum) {
    __shared__ int s[512];
    int tid = threadIdx.x;
    int gid = blockIdx.x * 512 + tid;
    int x = (gid < NN) ? cnt[gid] : 0;
    s[tid] = x;
    __syncthreads();
    for (int off = 1; off < 512; off <<= 1) {
        int t = (tid >= off) ? s[tid - off] : 0;
        __syncthreads();
        s[tid] += t;
        __syncthreads();
    }
    if (gid < NN) start[gid] = s[tid] - x;           // exclusive within block
    if (tid == 511) bsum[blockIdx.x] = s[511];
}

__global__ __launch_bounds__(128) void k_scan2(int* __restrict__ bsum) {  // 98 -> exclusive, in place
    __shared__ int s[128];
    int tid = threadIdx.x;
    int x = (tid < 98) ? bsum[tid] : 0;
    s[tid] = x;
    __syncthreads();
    for (int off = 1; off < 128; off <<= 1) {
        int t = (tid >= off) ? s[tid - off] : 0;
        __syncthreads();
        s[tid] += t;
        __syncthreads();
    }
    if (tid < 98) bsum[tid] = s[tid] - x;
}

__global__ __launch_bounds__(512) void k_scan3(const int* __restrict__ bsum,
                                               int* __restrict__ start, int* __restrict__ cursor) {
    int gid = blockIdx.x * 512 + threadIdx.x;
    if (gid < NN) {
        int s = start[gid] + bsum[blockIdx.x];
        start[gid] = s;
        cursor[gid] = s;
    } else if (gid == NN) {
        start[NN] = NE;                               // sentinel
    }
}

// ---------- K5c: per-edge score + scatter packed {e1, ee} record ----------
__global__ __launch_bounds__(256) void k_edge2(const float* __restrict__ s3, const float* __restrict__ s4,
                                               const float* __restrict__ ecs,
                                               const void* __restrict__ edge, const void* __restrict__ row_resort,
                                               const int* __restrict__ iflag,
                                               int* __restrict__ cursor, float2* __restrict__ pairs,
                                               float* __restrict__ edge_e /* = out2 */) {
    int e = blockIdx.x * 256 + threadIdx.x;           // thread per edge
    int i64 = *iflag;
    int e0 = ldi(edge, e, i64);
    int e1 = ldi(edge, (size_t)NE + e, i64);
    int rr = ldi(row_resort, e, i64);
    float rs = s3[rr] + s4[e1];
    float l = rs > 0.f ? rs : ALPHA * rs;
    float ee = expf(-l) * ecs[rr];
    edge_e[e] = ee;                                   // numerator for out2
    int pos = atomicAdd(&cursor[e0], 1);              // L2-resident int atomic
    pairs[pos] = make_float2(__int_as_float(e1), ee);
}

// ---------- K6: gather-aggregate per node; fused rowsum + divide + elu ----------
__global__ __launch_bounds__(256) void k_agg(const float* __restrict__ h,
                                             const float2* __restrict__ pairs,
                                             const int* __restrict__ start,
                                             float* __restrict__ ersum,
                                             float* __restrict__ out0) {
    int lane = threadIdx.x & 63;
    int v = blockIdx.x * 4 + (threadIdx.x >> 6);      // 12500*4 = NN exact
    int a = start[v], b = start[v + 1];
    float acc = 0.f, rs = 0.f;
    int j = a;
    for (; j + 4 <= b; j += 4) {                      // 4 independent 256B gathers in flight
        float2 p0 = pairs[j + 0], p1 = pairs[j + 1], p2 = pairs[j + 2], p3 = pairs[j + 3];
        float h0 = h[(size_t)__float_as_int(p0.x) * FOUT + lane];
        float h1 = h[(size_t)__float_as_int(p1.x) * FOUT + lane];
        float h2 = h[(size_t)__float_as_int(p2.x) * FOUT + lane];
        float h3 = h[(size_t)__float_as_int(p3.x) * FOUT + lane];
        rs += (p0.y + p1.y) + (p2.y + p3.y);
        acc += p0.y * h0 + p1.y * h1 + p2.y * h2 + p3.y * h3;
    }
    for (; j < b; j++) {
        float2 p = pairs[j];
        rs += p.y;
        acc += p.y * h[(size_t)__float_as_int(p.x) * FOUT + lane];
    }
    rs += (rs == 0.f) ? 1.f : 0.f;                    // empty-segment fixup (ee>0 otherwise)
    float hp = acc / rs;
    out0[(size_t)v * FOUT + lane] = hp > 0.f ? hp : expm1f(hp);
    if (lane == 0) ersum[v] = rs;                     // fixed rowsum, plain store
}

// ---------- K7: out2 = numerator / rowsum, in place ----------
__global__ void k_att(const void* __restrict__ edge, const int* __restrict__ iflag,
                      const float* __restrict__ ersum, float* __restrict__ out2) {
    int e = blockIdx.x * 256 + threadIdx.x;           // 6250*256 = NE exact
    out2[e] = out2[e] / ersum[ldi(edge, e, *iflag)];
}

// ---------- K8: out1 = float(edge), runs LAST ----------
__global__ void k_edgecopy(const void* __restrict__ edge, const int* __restrict__ iflag,
                           float* __restrict__ out1) {
    int i = blockIdx.x * 256 + threadIdx.x;           // 12500*256 = 2*NE exact
    int i64 = *iflag;
    int v = i64 ? (int)((const long long*)edge)[i] : ((const int*)edge)[i];
    out1[i] = (float)v;
}

extern "C" void kernel_launch(void* const* d_in, const int* in_sizes, int n_in,
                              void* d_out, int out_size, void* d_ws, size_t ws_size,
                              hipStream_t stream) {
    // Resolve inputs by element count (all distinct).
    int ix[3] = {0, 1, 2}; int nx = 0;
    int iE = 3, iCol = 4, iRowI = 5, iRes = 6, iW = 8, iA1 = 9, iA2 = 10;
    bool a1seen = false;
    for (int i = 0; i < n_in; i++) {
        int s = in_sizes[i];
        if (s == NN * FIN) { if (nx < 3) ix[nx++] = i; }
        else if (s == 2 * NE) iE = i;
        else if (s == 2 * NN) iCol = i;
        else if (s == NN) iRowI = i;
        else if (s == NE) iRes = i;
        else if (s == FIN * FOUT) iW = i;
        else if (s == 2 * FOUT) { if (!a1seen) { iA1 = i; a1seen = true; } else iA2 = i; }
    }
    const float* input = (const float*)d_in[ix[0]];
    const float* p_h   = (const float*)d_in[ix[1]];
    const float* new_h = (const float*)d_in[ix[2]];
    const void* edge       = d_in[iE];
    const void* edge_col   = d_in[iCol];
    const void* row_i      = d_in[iRowI];
    const void* row_resort = d_in[iRes];
    const float* W  = (const float*)d_in[iW];
    const float* a1 = (const float*)d_in[iA1];
    const float* a2 = (const float*)d_in[iA2];

    // Outputs are FLOAT32, concatenated.
    float* out0 = (float*)d_out;                      // N*FOUT
    float* out1 = out0 + (size_t)NN * FOUT;           // 2*NE
    float* out2 = out1 + (size_t)2 * NE;              // NE (edge_e numerator, then in-place divide)

    // ws layout (~27.8 MB; evidence from round-3 says ws >= ~34 MB)
    float*  h      = (float*)d_ws;                    // 3.2M
    float2* pairs  = (float2*)(h + (size_t)NN * FOUT);// 1.6M float2 (12.8 MB)
    float*  s1     = (float*)(pairs + NE);
    float*  s2     = s1 + NN;
    float*  s3     = s2 + NN;
    float*  s4     = s3 + NN;
    float*  ec     = s4 + NN;                         // reused in place as ex
    float*  ecs    = ec + NN;
    float*  mseg   = ecs + NN;                        // zeroed (atomicMax uint bits)
    float*  ssum   = mseg + NN;                       // zeroed
    int*    cnt    = (int*)(ssum + NN);               // zeroed (contiguous with above)
    int*    start  = cnt + NN;                        // NN+1 (sentinel)
    int*    cursor = start + NN + 1;                  // NN
    int*    bsum   = cursor + NN;                     // 128
    float*  ersum  = (float*)(bsum + 128);            // NN (plain stores, no zero needed)
    float*  u      = ersum + NN;                      // 512
    int*    iflag  = (int*)(u + 512);

    hipMemsetAsync(mseg, 0, (size_t)3 * NN * sizeof(float), stream);  // mseg, ssum, cnt

    k_sniff<<<1, 256, 0, stream>>>((const int*)edge, iflag);
    k_u<<<1, 128, 0, stream>>>(W, a1, a2, u);
    k_gemm<<<NN / 16, 256, 0, stream>>>(input, W, h);
    k_svec<<<NN / 4, 256, 0, stream>>>(input, p_h, new_h, u, s1, s2, s3, s4);
    k_colscore<<<(NN + 255) / 256, 256, 0, stream>>>(s1, s2, edge_col, row_i, iflag, ec, (unsigned int*)mseg);
    k_expsum<<<(NN + 255) / 256, 256, 0, stream>>>(ec, (const unsigned int*)mseg, row_i, iflag, ssum);
    k_norm<<<(NN + 255) / 256, 256, 0, stream>>>(ec, ssum, row_i, iflag, ecs);
    k_hist<<<NE / 256, 256, 0, stream>>>(edge, iflag, cnt);
    k_scan1<<<98, 512, 0, stream>>>(cnt, start, bsum);
    k_scan2<<<1, 128, 0, stream>>>(bsum);
    k_scan3<<<98, 512, 0, stream>>>(bsum, start, cursor);
    k_edge2<<<NE / 256, 256, 0, stream>>>(s3, s4, ecs, edge, row_resort, iflag, cursor, pairs, out2);
    k_agg<<<NN / 4, 256, 0, stream>>>(h, pairs, start, ersum, out0);
    k_att<<<NE / 256, 256, 0, stream>>>(edge, iflag, ersum, out2);
    k_edgecopy<<<2 * NE / 256, 256, 0, stream>>>(edge, iflag, out1);
}